// Round 10
// baseline (14260.387 us; speedup 1.0000x reference)
//
#include <hip/hip_runtime.h>
#include <hip/hip_bf16.h>

#define NEGINF -1e30f

typedef __attribute__((ext_vector_type(8))) short short8;
typedef __attribute__((ext_vector_type(4))) short short4_t;
typedef __attribute__((ext_vector_type(4))) float f32x4;

// Clamp-free: IEEE inf semantics give exact limits (exp->inf => rcp->0), NaN-free.
__device__ __forceinline__ float fast_sigmoid(float x) {
    return __builtin_amdgcn_rcpf(1.f + __expf(-x));
}
__device__ __forceinline__ float fast_tanh(float x) {
    return 1.f - 2.f * __builtin_amdgcn_rcpf(1.f + __expf(2.f * x));
}
// round-to-nearest-even f32 -> bf16 bits
__device__ __forceinline__ short f2bf(float f) {
    unsigned u = __float_as_uint(f);
    return (short)((u + 0x7fff + ((u >> 16) & 1)) >> 16);
}
__device__ __forceinline__ float bf2f(short b) {
    return __uint_as_float(((unsigned)(unsigned short)b) << 16);
}

// LDS-only workgroup barrier (proven R3-R9): waits lgkmcnt only; in-flight global
// loads/stores are NOT drained. Safe when all cross-thread traffic goes through LDS.
__device__ __forceinline__ void bar_lds() {
    asm volatile("s_waitcnt lgkmcnt(0)\n\ts_barrier" ::: "memory");
}

// ---------------- Tiled f32 GEMM (pipelined): out[M,N] = A[M,K] @ W[N,K]^T + bias ----
// bx == nsplit*2 (last x-tile) blocks instead convert w_ih_f/w_ih_b to bf16 (wbf).
// Row-tiles past lengths[batch] are skipped. mode 1: out = sigmoid(.)*A.
__global__ __launch_bounds__(256) void gemm_bias(
    const float* __restrict__ A,
    const float* __restrict__ W1, const float* __restrict__ b1, float* __restrict__ out1,
    const float* __restrict__ W2, const float* __restrict__ b2, float* __restrict__ out2,
    const int* __restrict__ lengths,
    const float* __restrict__ cvt1, const float* __restrict__ cvt2,
    unsigned short* __restrict__ wbf,
    int M, int N, int K, int nsplit, int mode, int nconv) {
    const int tid = threadIdx.x;
    int bx = blockIdx.x;
    if (bx >= nconv) {  // conversion tiles: w_ih f32 -> bf16 (runs for all blockIdx.y)
        const int total = 384 * 512;
        for (int i = blockIdx.y * 256 + tid; i < total; i += 32 * 256) {
            wbf[i] = (unsigned short)f2bf(cvt1[i]);
            wbf[total + i] = (unsigned short)f2bf(cvt2[i]);
        }
        return;
    }
    const int m0 = blockIdx.y * 64;
    if ((m0 & 511) >= lengths[m0 >> 9]) return;  // uniform per block; rows unread
    __shared__ __align__(16) float At[2][16][64];
    __shared__ __align__(16) float Wt[2][16][64];
    const float* W = W1; const float* bias = b1; float* out = out1;
    int n0;
    if (bx < nsplit) {
        n0 = bx * 64;
    } else {
        W = W2; bias = b2; out = out2;
        n0 = (bx - nsplit) * 64;
    }
    const int tx = tid & 15;
    const int ty = tid >> 4;
    float acc[4][4];
#pragma unroll
    for (int r = 0; r < 4; r++)
#pragma unroll
        for (int c = 0; c < 4; c++) acc[r][c] = 0.f;

    const int lr = tid >> 2;
    const int lc = (tid & 3) * 4;

    float4 a = *(const float4*)(A + (size_t)(m0 + lr) * K + lc);
    float4 w = *(const float4*)(W + (size_t)(n0 + lr) * K + lc);

    for (int k0 = 0; k0 < K; k0 += 16) {
        const int cur = (k0 >> 4) & 1;
        At[cur][lc + 0][lr] = a.x; At[cur][lc + 1][lr] = a.y;
        At[cur][lc + 2][lr] = a.z; At[cur][lc + 3][lr] = a.w;
        Wt[cur][lc + 0][lr] = w.x; Wt[cur][lc + 1][lr] = w.y;
        Wt[cur][lc + 2][lr] = w.z; Wt[cur][lc + 3][lr] = w.w;
        if (k0 + 16 < K) {
            a = *(const float4*)(A + (size_t)(m0 + lr) * K + k0 + 16 + lc);
            w = *(const float4*)(W + (size_t)(n0 + lr) * K + k0 + 16 + lc);
        }
        bar_lds();
#pragma unroll
        for (int kk = 0; kk < 16; kk++) {
            float4 av = *(const float4*)&At[cur][kk][ty * 4];
            float4 wv = *(const float4*)&Wt[cur][kk][tx * 4];
            const float* ap = (const float*)&av;
            const float* wp = (const float*)&wv;
#pragma unroll
            for (int r = 0; r < 4; r++)
#pragma unroll
                for (int c = 0; c < 4; c++) acc[r][c] += ap[r] * wp[c];
        }
    }
    float4 bb = *(const float4*)(bias + n0 + tx * 4);
    const float* bp = (const float*)&bb;
#pragma unroll
    for (int r = 0; r < 4; r++) {
        int m = m0 + ty * 4 + r;
        float4 o;
        float* op = (float*)&o;
#pragma unroll
        for (int c = 0; c < 4; c++) op[c] = acc[r][c] + bp[c];
        if (mode == 1) {
            float4 av = *(const float4*)(A + (size_t)m * K + n0 + tx * 4);
            const float* ap = (const float*)&av;
#pragma unroll
            for (int c = 0; c < 4; c++) op[c] = fast_sigmoid(op[c]) * ap[c];
        }
        *(float4*)(out + (size_t)m * N + n0 + tx * 4) = o;
    }
}

// ---------------- Attention: scores(tanh-dot) -> masked softmax -> C = attn @ v ------
__global__ __launch_bounds__(256) void attn_kernel(
    const float* __restrict__ v, const int* __restrict__ lengths,
    const float* __restrict__ own, const float* __restrict__ comp,
    const float* __restrict__ v_attn, float* __restrict__ inp) {
    const int L = 512, D = 256, H = 128;
    const int b = blockIdx.x >> 9;
    const int q = blockIdx.x & 511;
    const int len = lengths[b];
    if (q >= len) return;
    const int tid = threadIdx.x;
    const float K2E = 2.8853900817779268f;  // 2*log2(e)
    __shared__ float oK[128];
    __shared__ float va2[128];
    __shared__ float sc[512];
    __shared__ float red[256];
    if (tid < 128) {
        oK[tid] = K2E * own[((size_t)(b * L + q)) * H + tid];
        va2[tid] = -2.f * v_attn[tid];
    }
    red[tid] = (tid < 128) ? v_attn[tid] : 0.f;
    __syncthreads();
    for (int off = 128; off > 0; off >>= 1) {
        if (tid < off) red[tid] += red[tid + off];
        __syncthreads();
    }
    const float VA_SUM = red[0];
    __syncthreads();
    float s2[2];
    float smax = NEGINF;
#pragma unroll
    for (int slot = 0; slot < 2; slot++) {
        int k = tid + slot * 256;
        float s = NEGINF;
        if (k < len) {
            const float* cp = comp + ((size_t)(b * L + k)) * H;
            float acc = VA_SUM;
#pragma unroll 4
            for (int h = 0; h < H; h += 4) {
                float4 c4 = *(const float4*)(cp + h);
                float r0 = __builtin_amdgcn_rcpf(1.f + exp2f(fmaf(c4.x, K2E, oK[h + 0])));
                float r1 = __builtin_amdgcn_rcpf(1.f + exp2f(fmaf(c4.y, K2E, oK[h + 1])));
                float r2 = __builtin_amdgcn_rcpf(1.f + exp2f(fmaf(c4.z, K2E, oK[h + 2])));
                float r3 = __builtin_amdgcn_rcpf(1.f + exp2f(fmaf(c4.w, K2E, oK[h + 3])));
                acc = fmaf(va2[h + 0], r0, acc);
                acc = fmaf(va2[h + 1], r1, acc);
                acc = fmaf(va2[h + 2], r2, acc);
                acc = fmaf(va2[h + 3], r3, acc);
            }
            s = acc;
        }
        s2[slot] = s;
        smax = fmaxf(smax, s);
    }
    red[tid] = smax;
    __syncthreads();
    for (int off = 128; off > 0; off >>= 1) {
        if (tid < off) red[tid] = fmaxf(red[tid], red[tid + off]);
        __syncthreads();
    }
    float mx = red[0];
    __syncthreads();
    float lsum = 0.f;
#pragma unroll
    for (int slot = 0; slot < 2; slot++) {
        float e = __expf(s2[slot] - mx);
        sc[tid + slot * 256] = e;
        lsum += e;
    }
    red[tid] = lsum;
    __syncthreads();
    for (int off = 128; off > 0; off >>= 1) {
        if (tid < off) red[tid] += red[tid + off];
        __syncthreads();
    }
    float inv = __builtin_amdgcn_rcpf(red[0]);
    float a0 = 0.f, a1 = 0.f, a2 = 0.f, a3 = 0.f;
    const float* vb = v + ((size_t)b * L) * D + tid;
#pragma unroll 4
    for (int k = 0; k < L; k += 4) {
        a0 += sc[k + 0] * vb[(size_t)(k + 0) * D];
        a1 += sc[k + 1] * vb[(size_t)(k + 1) * D];
        a2 += sc[k + 2] * vb[(size_t)(k + 2) * D];
        a3 += sc[k + 3] * vb[(size_t)(k + 3) * D];
    }
    float accum = ((a0 + a1) + (a2 + a3)) * inv;
    size_t row = ((size_t)(b * L + q)) * 512;
    inp[row + 256 + tid] = accum;
    inp[row + tid] = v[((size_t)(b * L + q)) * D + tid];
}

// ---------------- Fused GRU: xp projection (MFMA, interleaved) + recurrence ----------
// One block per (dir, batch), 512 threads = 8 waves. The separate xp GEMM is gone:
// while running chunk c's 16 steps, each wave also issues 3 MFMAs/step computing
// chunk c+1's xp = gated @ w_ih^T (A = bf16(gated) rows staged in LDS, layout
// A[m=lane&15][k=quad*8+j] — HW-proven in R8; B = bf16(w_ih) streamed from L2 with
// rolling 1-step prefetch, same per-lane pattern as the proven w_hh frags).
// xp accumulates in registers across the chunk, committed to parity xbuf at chunk end.
// Recurrence itself unchanged from R8/R9 (operand-swapped MFMA, 1 bar_lds/step).
__global__ __launch_bounds__(512, 2) void gru_kernel(
    const float* __restrict__ gated, const unsigned short* __restrict__ wihbf,
    const float* __restrict__ w_hh_f, const float* __restrict__ w_hh_b,
    const float* __restrict__ b_hh_f, const float* __restrict__ b_hh_b,
    const int* __restrict__ lengths, float* __restrict__ out) {
    const int L = 512, H = 128;
    const int dir = blockIdx.x >> 2;
    const int b = blockIdx.x & 3;
    const float* w_hh = dir ? w_hh_b : w_hh_f;
    const float* b_hh = dir ? b_hh_b : b_hh_f;
    const unsigned short* wih = wihbf + (size_t)dir * 384 * 512;
    const int tid = threadIdx.x;
    const int wave = tid >> 6;
    const int lane = tid & 63;
    const int mrow = lane & 15;
    const int quad = lane >> 4;
    const int jj = 16 * wave + lane;  // gate dim for lanes lane<16

    __shared__ __align__(16) short hbuf[2][256];      // 1 KB
    __shared__ __align__(16) float xbuf[2][16 * 384]; // 48 KB (xp parity buffers)
    __shared__ __align__(16) short gbf[2][16 * 520];  // 33 KB (gated bf16, padded 520)
    __shared__ __align__(16) float obuf[16 * 128];    // 8 KB

    // ---- recurrence B-fragments (w_hh), proven R8 pattern ----
    short8 wb[3][4];
#pragma unroll
    for (int g = 0; g < 3; g++) {
        int row = g * 128 + 16 * wave + mrow;
#pragma unroll
        for (int kt = 0; kt < 4; kt++) {
            const float* wp = w_hh + (size_t)row * H + kt * 32 + quad * 8;
            float4 w0 = *(const float4*)(wp);
            float4 w1 = *(const float4*)(wp + 4);
            float wv[8] = {w0.x, w0.y, w0.z, w0.w, w1.x, w1.y, w1.z, w1.w};
            short8 hi8;
#pragma unroll
            for (int k = 0; k < 8; k++) hi8[k] = f2bf(wv[k]);
            wb[g][kt] = hi8;
        }
    }
    float br = 0.f, bz = 0.f, bn = 0.f, hcur = 0.f;
    if (lane < 16) {
        br = b_hh[jj];
        bz = b_hh[128 + jj];
        bn = b_hh[256 + jj];
    }

    const int len = lengths[b];
    for (int idx = tid; idx < (L - len) * 128; idx += 512) {  // zero masked tail
        int tt = len + (idx >> 7);
        int kk = idx & 127;
        out[((size_t)(b * L + tt)) * 256 + dir * 128 + kk] = 0.f;
    }
    if (tid < 256) hbuf[0][tid] = 0;

    const int nch = (len + 15) >> 4;
    // gated staging geometry: 2048 float4/chunk, 4 per thread
    int srow[4], scol[4];
#pragma unroll
    for (int k = 0; k < 4; k++) {
        int i = tid + k * 512;
        srow[k] = i >> 7;
        scol[k] = (i & 127) * 4;
    }
    // xp-gemm geometry: wave owns ncols NB(nt) = (wave*3+nt)*16 + mrow
    int NB[3];
#pragma unroll
    for (int nt = 0; nt < 3; nt++) NB[nt] = (wave * 3 + nt) * 16 + mrow;
    const int bbase = (mrow & 1) * 128 + quad * 8;   // h A-frag (row0=hi, row1=lo)
    const int gread = mrow * 520 + quad * 8;         // gated A-frag base (+32*kt)

    // ---- stage gated chunk 0 ----
    float4 g[4];
#pragma unroll
    for (int k = 0; k < 4; k++) {
        int tt = dir ? (len - 1 - srow[k]) : srow[k];
        g[k] = *(const float4*)&gated[((size_t)(b * L + tt)) * 512 + scol[k]];
    }
#pragma unroll
    for (int k = 0; k < 4; k++) {
        short4_t s4;
        s4[0] = f2bf(g[k].x); s4[1] = f2bf(g[k].y);
        s4[2] = f2bf(g[k].z); s4[3] = f2bf(g[k].w);
        *(short4_t*)&gbf[0][srow[k] * 520 + scol[k]] = s4;
    }
    // prefetch gated chunk 1
    if (nch > 1) {
        int rc = min(16, len - 16);
#pragma unroll
        for (int k = 0; k < 4; k++) {
            if (srow[k] < rc) {
                int tt = dir ? (len - 1 - (16 + srow[k])) : (16 + srow[k]);
                g[k] = *(const float4*)&gated[((size_t)(b * L + tt)) * 512 + scol[k]];
            }
        }
    }
    bar_lds();  // gbf[0] visible

    // ---- burst: xp(chunk 0) -> xbuf[0] ----
    {
        f32x4 xacc[3];
#pragma unroll
        for (int nt = 0; nt < 3; nt++) xacc[nt] = (f32x4){0.f, 0.f, 0.f, 0.f};
        short8 wf[2][3];
#pragma unroll
        for (int nt = 0; nt < 3; nt++)
            wf[0][nt] = *(const short8*)&wih[(size_t)NB[nt] * 512 + quad * 8];
        for (int kt = 0; kt < 16; kt++) {
            if (kt < 15) {
#pragma unroll
                for (int nt = 0; nt < 3; nt++)
                    wf[(kt + 1) & 1][nt] = *(const short8*)&wih[(size_t)NB[nt] * 512 + (kt + 1) * 32 + quad * 8];
            }
            short8 ga = *(const short8*)&gbf[0][gread + kt * 32];
#pragma unroll
            for (int nt = 0; nt < 3; nt++)
                xacc[nt] = __builtin_amdgcn_mfma_f32_16x16x32_bf16(ga, wf[kt & 1][nt], xacc[nt], 0, 0, 0);
        }
#pragma unroll
        for (int nt = 0; nt < 3; nt++)
#pragma unroll
            for (int r = 0; r < 4; r++)
                xbuf[0][(quad * 4 + r) * 384 + NB[nt]] = xacc[nt][r];
    }

    int par = 0;
    f32x4 xacc[3];
    short8 wf[2][3];
    for (int c = 0; c < nch; c++) {
        const int cnt = min(16, len - c * 16);
        const int pc = c & 1, pn = pc ^ 1;
        const bool do_xp = (c + 1 < nch);
        // commit gated regs (chunk c+1) -> gbf[pn]
        if (do_xp) {
            int rc = min(16, len - (c + 1) * 16);
#pragma unroll
            for (int k = 0; k < 4; k++) {
                if (srow[k] < rc) {
                    short4_t s4;
                    s4[0] = f2bf(g[k].x); s4[1] = f2bf(g[k].y);
                    s4[2] = f2bf(g[k].z); s4[3] = f2bf(g[k].w);
                    *(short4_t*)&gbf[pn][srow[k] * 520 + scol[k]] = s4;
                }
            }
        }
        // flush previous chunk's outputs
        if (c > 0) {
            int p0 = (c - 1) * 16;
            for (int i = tid; i < 16 * 128; i += 512) {
                int ss = i >> 7, kk = i & 127;
                int tt = dir ? (len - 1 - (p0 + ss)) : (p0 + ss);
                out[((size_t)(b * L + tt)) * 256 + dir * 128 + kk] = obuf[i];
            }
        }
        // prefetch gated chunk c+2
        if (c + 2 < nch) {
            int rc = min(16, len - (c + 2) * 16);
            int base = (c + 2) * 16;
#pragma unroll
            for (int k = 0; k < 4; k++) {
                if (srow[k] < rc) {
                    int tt = dir ? (len - 1 - (base + srow[k])) : (base + srow[k]);
                    g[k] = *(const float4*)&gated[((size_t)(b * L + tt)) * 512 + scol[k]];
                }
            }
        }
        bar_lds();  // xbuf[pc] + gbf[pn] visible; prev obuf reads complete
        if (do_xp) {
#pragma unroll
            for (int nt = 0; nt < 3; nt++) {
                xacc[nt] = (f32x4){0.f, 0.f, 0.f, 0.f};
                wf[0][nt] = *(const short8*)&wih[(size_t)NB[nt] * 512 + quad * 8];
            }
        }
        const float* xb = xbuf[pc];
        for (int s = 0; s < cnt; s++) {
            float xr, xz, xn;
            if (lane < 16) {
                xr = xb[s * 384 + jj];
                xz = xb[s * 384 + 128 + jj];
                xn = xb[s * 384 + 256 + jj];
            }
            short8 af[4];
#pragma unroll
            for (int kt = 0; kt < 4; kt++) af[kt] = *(const short8*)&hbuf[par][bbase + kt * 32];
            f32x4 acc[3];
#pragma unroll
            for (int gg = 0; gg < 3; gg++) acc[gg] = (f32x4){0.f, 0.f, 0.f, 0.f};
#pragma unroll
            for (int kt = 0; kt < 4; kt++)
#pragma unroll
                for (int gg = 0; gg < 3; gg++)
                    acc[gg] = __builtin_amdgcn_mfma_f32_16x16x32_bf16(af[kt], wb[gg][kt], acc[gg], 0, 0, 0);
            if (do_xp) {  // interleaved xp MFMAs for chunk c+1 (kt = s; cnt==16 here)
                if (s < 15) {
#pragma unroll
                    for (int nt = 0; nt < 3; nt++)
                        wf[(s + 1) & 1][nt] = *(const short8*)&wih[(size_t)NB[nt] * 512 + (s + 1) * 32 + quad * 8];
                }
                short8 ga = *(const short8*)&gbf[pn][gread + s * 32];
#pragma unroll
                for (int nt = 0; nt < 3; nt++)
                    xacc[nt] = __builtin_amdgcn_mfma_f32_16x16x32_bf16(ga, wf[s & 1][nt], xacc[nt], 0, 0, 0);
            }
            if (lane < 16) {
                float hr = acc[0][0] + acc[0][1] + br;
                float hz = acc[1][0] + acc[1][1] + bz;
                float hh = acc[2][0] + acc[2][1] + bn;
                float r = fast_sigmoid(xr + hr);
                float z = fast_sigmoid(xz + hz);
                float n = fast_tanh(xn + r * hh);
                float hn = (1.f - z) * n + z * hcur;
                hcur = hn;
                short hb = f2bf(hn);
                hbuf[par ^ 1][jj] = hb;
                hbuf[par ^ 1][128 + jj] = f2bf(hn - bf2f(hb));
                obuf[s * 128 + jj] = hn;
            }
            par ^= 1;
            bar_lds();  // hbuf[par] ready; single barrier per step
        }
        if (do_xp) {  // commit xp(c+1) to xbuf[pn]; next chunk-top bar covers visibility
#pragma unroll
            for (int nt = 0; nt < 3; nt++)
#pragma unroll
                for (int r = 0; r < 4; r++)
                    xbuf[pn][(quad * 4 + r) * 384 + NB[nt]] = xacc[nt][r];
        }
    }
    // final flush (last chunk, possibly partial)
    {
        int p0 = (nch - 1) * 16;
        int pcnt = len - p0;
        for (int i = tid; i < pcnt * 128; i += 512) {
            int ss = i >> 7, kk = i & 127;
            int tt = dir ? (len - 1 - (p0 + ss)) : (p0 + ss);
            out[((size_t)(b * L + tt)) * 256 + dir * 128 + kk] = obuf[i];
        }
    }
}

extern "C" void kernel_launch(void* const* d_in, const int* in_sizes, int n_in,
                              void* d_out, int out_size, void* d_ws, size_t ws_size,
                              hipStream_t stream) {
    const int B = 4, L = 512, D = 256, H = 128;
    const int M = B * L;  // 2048

    const float* v      = (const float*)d_in[0];
    const int* lengths  = (const int*)d_in[1];
    const float* own_W  = (const float*)d_in[3];
    const float* own_b  = (const float*)d_in[4];
    const float* comp_W = (const float*)d_in[5];
    const float* comp_b = (const float*)d_in[6];
    const float* v_attn = (const float*)d_in[7];
    const float* gate_W = (const float*)d_in[8];
    const float* gate_b = (const float*)d_in[9];
    const float* w_ih_f = (const float*)d_in[10];
    const float* w_hh_f = (const float*)d_in[11];
    const float* b_hh_f = (const float*)d_in[13];
    const float* w_ih_b = (const float*)d_in[14];
    const float* w_hh_b = (const float*)d_in[15];
    const float* b_hh_b = (const float*)d_in[17];

    float* ws   = (float*)d_ws;
    float* own  = ws;                        // [2048,128]
    float* comp = own + (size_t)M * H;       // [2048,128]
    float* inp  = comp + (size_t)M * H;      // [2048,512]
    float* gated = inp + (size_t)M * 512;    // [2048,512]
    unsigned short* wihbf = (unsigned short*)(gated + (size_t)M * 512);  // [2][384][512] bf16
    float* out  = (float*)d_out;             // [2048,256]

    // 1: own & comp projections + w_ih bf16 conversion (tile bx==4), one launch
    gemm_bias<<<dim3(5, M / 64), 256, 0, stream>>>(
        v, own_W, own_b, own, comp_W, comp_b, comp, lengths,
        w_ih_f, w_ih_b, wihbf, M, H, D, 2, 0, 4);
    // 2: attention -> inp = [v, C]
    attn_kernel<<<dim3(B * L), 256, 0, stream>>>(v, lengths, own, comp, v_attn, inp);
    // 3: gate
    gemm_bias<<<dim3(8, M / 64), 256, 0, stream>>>(
        inp, gate_W, gate_b, gated, gate_W, gate_b, gated, lengths,
        nullptr, nullptr, nullptr, M, 512, 512, 8, 1, 8);
    // 4: fused GRU (computes its own xp from gated + wihbf; gemm4 deleted)
    gru_kernel<<<dim3(8), 512, 0, stream>>>(
        gated, wihbf, w_hh_f, w_hh_b, b_hh_f, b_hh_b, lengths, out);
}

// Round 11
// 434.660 us; speedup vs baseline: 32.8081x; 32.8081x over previous
//
#include <hip/hip_runtime.h>
#include <hip/hip_bf16.h>

#define NEGINF -1e30f

typedef __attribute__((ext_vector_type(8))) short short8;
typedef __attribute__((ext_vector_type(4))) float f32x4;

// Clamp-free: IEEE inf semantics give exact limits (exp->inf => rcp->0), NaN-free.
__device__ __forceinline__ float fast_sigmoid(float x) {
    return __builtin_amdgcn_rcpf(1.f + __expf(-x));
}
__device__ __forceinline__ float fast_tanh(float x) {
    return 1.f - 2.f * __builtin_amdgcn_rcpf(1.f + __expf(2.f * x));
}
// round-to-nearest-even f32 -> bf16 bits
__device__ __forceinline__ short f2bf(float f) {
    unsigned u = __float_as_uint(f);
    return (short)((u + 0x7fff + ((u >> 16) & 1)) >> 16);
}
__device__ __forceinline__ float bf2f(short b) {
    return __uint_as_float(((unsigned)(unsigned short)b) << 16);
}

// LDS-only workgroup barrier (proven R3-R9): waits lgkmcnt only; in-flight global
// loads/stores are NOT drained. Safe when all cross-thread traffic goes through LDS.
__device__ __forceinline__ void bar_lds() {
    asm volatile("s_waitcnt lgkmcnt(0)\n\ts_barrier" ::: "memory");
}

// ---------------- Tiled f32 GEMM (pipelined): out[M,N] = A[M,K] @ W[N,K]^T + bias ----
// Register-prefetch + parity LDS buffers + single LDS-only barrier per k-iter.
// Row-tiles entirely past lengths[batch] are skipped (outputs unread downstream).
// Two weight/bias/out sets selectable by block tile. mode 1: out = sigmoid(.)*A.
__global__ __launch_bounds__(256) void gemm_bias(
    const float* __restrict__ A,
    const float* __restrict__ W1, const float* __restrict__ b1, float* __restrict__ out1,
    const float* __restrict__ W2, const float* __restrict__ b2, float* __restrict__ out2,
    const int* __restrict__ lengths,
    int M, int N, int K, int nsplit, int mode) {
    const int m0 = blockIdx.y * 64;
    if ((m0 & 511) >= lengths[m0 >> 9]) return;  // uniform per block; rows unread
    __shared__ __align__(16) float At[2][16][64];
    __shared__ __align__(16) float Wt[2][16][64];
    const int tid = threadIdx.x;
    int bx = blockIdx.x;
    const float* W = W1; const float* bias = b1; float* out = out1;
    int n0;
    if (bx < nsplit) {
        n0 = bx * 64;
    } else {
        W = W2; bias = b2; out = out2;
        n0 = (bx - nsplit) * 64;
    }
    const int tx = tid & 15;   // col group (4 cols)
    const int ty = tid >> 4;   // row group (4 rows)
    float acc[4][4];
#pragma unroll
    for (int r = 0; r < 4; r++)
#pragma unroll
        for (int c = 0; c < 4; c++) acc[r][c] = 0.f;

    const int lr = tid >> 2;          // 0..63 row within tile for loads
    const int lc = (tid & 3) * 4;     // k within tile for loads

    // preload k-tile 0
    float4 a = *(const float4*)(A + (size_t)(m0 + lr) * K + lc);
    float4 w = *(const float4*)(W + (size_t)(n0 + lr) * K + lc);

    for (int k0 = 0; k0 < K; k0 += 16) {
        const int cur = (k0 >> 4) & 1;
        // commit staged regs (vmcnt wait lands here; load had a full iter in flight)
        At[cur][lc + 0][lr] = a.x; At[cur][lc + 1][lr] = a.y;
        At[cur][lc + 2][lr] = a.z; At[cur][lc + 3][lr] = a.w;
        Wt[cur][lc + 0][lr] = w.x; Wt[cur][lc + 1][lr] = w.y;
        Wt[cur][lc + 2][lr] = w.z; Wt[cur][lc + 3][lr] = w.w;
        // prefetch k-tile k0+16 (stays in flight across bar_lds)
        if (k0 + 16 < K) {
            a = *(const float4*)(A + (size_t)(m0 + lr) * K + k0 + 16 + lc);
            w = *(const float4*)(W + (size_t)(n0 + lr) * K + k0 + 16 + lc);
        }
        bar_lds();  // single barrier per iter: parity buffer prevents WAR
#pragma unroll
        for (int kk = 0; kk < 16; kk++) {
            float4 av = *(const float4*)&At[cur][kk][ty * 4];
            float4 wv = *(const float4*)&Wt[cur][kk][tx * 4];
            const float* ap = (const float*)&av;
            const float* wp = (const float*)&wv;
#pragma unroll
            for (int r = 0; r < 4; r++)
#pragma unroll
                for (int c = 0; c < 4; c++) acc[r][c] += ap[r] * wp[c];
        }
    }
    float4 bb = *(const float4*)(bias + n0 + tx * 4);
    const float* bp = (const float*)&bb;
#pragma unroll
    for (int r = 0; r < 4; r++) {
        int m = m0 + ty * 4 + r;
        float4 o;
        float* op = (float*)&o;
#pragma unroll
        for (int c = 0; c < 4; c++) op[c] = acc[r][c] + bp[c];
        if (mode == 1) {
            float4 av = *(const float4*)(A + (size_t)m * K + n0 + tx * 4);
            const float* ap = (const float*)&av;
#pragma unroll
            for (int c = 0; c < 4; c++) op[c] = fast_sigmoid(op[c]) * ap[c];
        }
        *(float4*)(out + (size_t)m * N + n0 + tx * 4) = o;
    }
}

// ---------------- Attention, 8 queries per block (q-tiled) ---------------------------
// score(q,k) = sum_h va2_h / (1+exp2(K2E*(own_qh + comp_kh)))  [+ VA_SUM, which is
// constant over k and cancels in softmax]. |score| <= 3*sum|va| ~ 18 -> exp is safe
// in f32 with NO max pass (softmax shift-invariance). 8 q's per block amortize the
// comp (256 KB) and v (512 KB) L2 reads 8x vs the per-q version. oK is stored
// transposed [h][q] so the score inner loop reads it as wave-broadcast b128.
// Writes inp[b,q,:] = concat(v[b,q,:], C[b,q,:]); rows q >= len unread downstream.
__global__ __launch_bounds__(512) void attn_kernel(
    const float* __restrict__ v, const int* __restrict__ lengths,
    const float* __restrict__ own, const float* __restrict__ comp,
    const float* __restrict__ v_attn, float* __restrict__ inp) {
    const int L = 512, D = 256, H = 128;
    const int b = blockIdx.x >> 6;
    const int q0 = (blockIdx.x & 63) * 8;
    const int len = lengths[b];
    if (q0 >= len) return;  // whole q-tile unread downstream
    const int tid = threadIdx.x;
    const float K2E = 2.8853900817779268f;  // 2*log2(e)
    __shared__ __align__(16) float oKT[128 * 8];   // [h][q] = K2E*own (4 KB)
    __shared__ float va2s[128];                    // -2 * v_attn
    __shared__ __align__(16) float scf[512 * 12];  // [k][q], stride 12 (24 KB)
    __shared__ float inv8[8];

    for (int i = tid; i < 1024; i += 512) {
        int qq = i >> 7, hh = i & 127;
        oKT[hh * 8 + qq] = K2E * own[((size_t)(b * L + q0 + qq)) * H + hh];
    }
    if (tid < 128) va2s[tid] = -2.f * v_attn[tid];
    __syncthreads();

    // ---- scores: thread = k (k >= len lanes write zeros) ----
    {
        const int k = tid;
        float acc[8];
#pragma unroll
        for (int q = 0; q < 8; q++) acc[q] = 0.f;
        if (k < len) {
            const float* cp = comp + ((size_t)(b * L + k)) * H;
            for (int h = 0; h < 128; h += 4) {
                float4 c4 = *(const float4*)(cp + h);
                const float* cv = (const float*)&c4;
#pragma unroll
                for (int j = 0; j < 4; j++) {
                    float cK = cv[j] * K2E;
                    float va = va2s[h + j];
                    float4 o0 = *(const float4*)&oKT[(h + j) * 8];      // broadcast
                    float4 o1 = *(const float4*)&oKT[(h + j) * 8 + 4];  // broadcast
                    const float* op0 = (const float*)&o0;
                    const float* op1 = (const float*)&o1;
#pragma unroll
                    for (int q = 0; q < 4; q++) {
                        float r = __builtin_amdgcn_rcpf(1.f + exp2f(cK + op0[q]));
                        acc[q] = fmaf(va, r, acc[q]);
                    }
#pragma unroll
                    for (int q = 0; q < 4; q++) {
                        float r = __builtin_amdgcn_rcpf(1.f + exp2f(cK + op1[q]));
                        acc[4 + q] = fmaf(va, r, acc[4 + q]);
                    }
                }
            }
#pragma unroll
            for (int q = 0; q < 8; q++) acc[q] = __expf(acc[q]);  // bounded, no max pass
        }
        *(float4*)&scf[k * 12] = *(float4*)&acc[0];
        *(float4*)&scf[k * 12 + 4] = *(float4*)&acc[4];
    }
    __syncthreads();

    // ---- per-q denominators: wave w handles q = w ----
    {
        int w = tid >> 6, l = tid & 63;
        float s = 0.f;
#pragma unroll
        for (int kk = 0; kk < 8; kk++) s += scf[(l + kk * 64) * 12 + w];
#pragma unroll
        for (int off = 1; off < 64; off <<= 1) s += __shfl_xor(s, off);
        if (l == 0) inv8[w] = __builtin_amdgcn_rcpf(s);
    }
    __syncthreads();

    // ---- context: thread owns dim d for 4 q's (qh selects q group) ----
    {
        const int d = tid & 255;
        const int qh = tid >> 8;  // 0/1
        float c0 = 0.f, c1 = 0.f, c2 = 0.f, c3 = 0.f;
        const float* vb = v + ((size_t)b * L) * D + d;
        for (int k = 0; k < L; k += 2) {
            float v0 = vb[(size_t)k * D];
            float v1 = vb[(size_t)(k + 1) * D];
            float4 s0 = *(const float4*)&scf[k * 12 + qh * 4];        // broadcast
            float4 s1 = *(const float4*)&scf[(k + 1) * 12 + qh * 4];  // broadcast
            c0 += s0.x * v0 + s1.x * v1;
            c1 += s0.y * v0 + s1.y * v1;
            c2 += s0.z * v0 + s1.z * v1;
            c3 += s0.w * v0 + s1.w * v1;
        }
        float cc[4] = {c0, c1, c2, c3};
#pragma unroll
        for (int j = 0; j < 4; j++) {
            int q = q0 + qh * 4 + j;
            size_t row = ((size_t)(b * L + q)) * 512;
            inp[row + 256 + d] = cc[j] * inv8[qh * 4 + j];
            inp[row + d] = v[((size_t)(b * L + q)) * D + d];
        }
    }
}

// ---------------- Bidirectional GRU recurrence (operand-swapped MFMA, R9) -----------
// One block per (dir, batch), 512 threads = 8 waves. Wave w owns gate dims
// jj = 16w..16w+15. h is the A operand (row0 = h_hi, row1 = h_lo), W^T is the B
// operand; C[0][c]/C[1][c] land at col c = lane (lanes 0-15), regs 0/1 — the hp
// triplet arrives directly in the gate lane's own acc registers. Per step:
// MFMA -> gate ALU -> hbuf write -> ONE bar_lds. A = bf16(W) (absmax 0.0039 ok);
// h stays f32-exact via hi/lo rows. Chunked global I/O — zero global ops in steps.
__global__ __launch_bounds__(512, 2) void gru_kernel(
    const float* __restrict__ xp_f, const float* __restrict__ xp_b,
    const float* __restrict__ w_hh_f, const float* __restrict__ w_hh_b,
    const float* __restrict__ b_hh_f, const float* __restrict__ b_hh_b,
    const int* __restrict__ lengths, float* __restrict__ out) {
    const int L = 512, H = 128;
    const int dir = blockIdx.x >> 2;
    const int b = blockIdx.x & 3;
    const float* xp = dir ? xp_b : xp_f;
    const float* w_hh = dir ? w_hh_b : w_hh_f;
    const float* b_hh = dir ? b_hh_b : b_hh_f;
    const int tid = threadIdx.x;
    const int wave = tid >> 6;
    const int lane = tid & 63;
    const int mrow = lane & 15;
    const int quad = lane >> 4;
    const int jj = 16 * wave + lane;  // gate dim for lanes lane<16

    __shared__ __align__(16) short hbuf[2][256];   // [parity][hi 0..127 | lo 128..255]
    __shared__ __align__(16) float xbuf[16 * 384]; // xp chunk stage (24 KB)
    __shared__ __align__(16) float obuf[16 * 128]; // output stage (8 KB)

    // ---- B-fragments (weights): wave w, gate g, B[k][n] = W_hh[g*128+16w+n][k] ----
    short8 wb[3][4];
#pragma unroll
    for (int g = 0; g < 3; g++) {
        int row = g * 128 + 16 * wave + mrow;
#pragma unroll
        for (int kt = 0; kt < 4; kt++) {
            const float* wp = w_hh + (size_t)row * H + kt * 32 + quad * 8;
            float4 w0 = *(const float4*)(wp);
            float4 w1 = *(const float4*)(wp + 4);
            float wv[8] = {w0.x, w0.y, w0.z, w0.w, w1.x, w1.y, w1.z, w1.w};
            short8 hi8;
#pragma unroll
            for (int k = 0; k < 8; k++) hi8[k] = f2bf(wv[k]);
            wb[g][kt] = hi8;
        }
    }
    float br = 0.f, bz = 0.f, bn = 0.f, hcur = 0.f;
    if (lane < 16) {
        br = b_hh[jj];
        bz = b_hh[128 + jj];
        bn = b_hh[256 + jj];
    }

    const int len = lengths[b];
    // pre-zero masked tail: out[b, t, dir*128+k] = 0 for t in [len, L)
    for (int idx = tid; idx < (L - len) * 128; idx += 512) {
        int tt = len + (idx >> 7);
        int kk = idx & 127;
        out[((size_t)(b * L + tt)) * 256 + dir * 128 + kk] = 0.f;
    }
    if (tid < 256) hbuf[0][tid] = 0;

    // staging geometry: 1536 float4 per chunk, 3 per thread
    const int f1 = tid + 512, f2 = tid + 1024;
    const int sA = tid / 96, jA = (tid % 96) * 4;
    const int sB = f1 / 96, jB = (f1 % 96) * 4;
    const int sC = f2 / 96, jC = (f2 % 96) * 4;

    const int nch = (len + 15) >> 4;  // len >= 256 so chunk 0 is full
    float4 r0, r1, r2;
    {
        int tA = dir ? (len - 1 - sA) : sA;
        int tB = dir ? (len - 1 - sB) : sB;
        int tC = dir ? (len - 1 - sC) : sC;
        r0 = *(const float4*)&xp[((size_t)(b * L + tA)) * 384 + jA];
        r1 = *(const float4*)&xp[((size_t)(b * L + tB)) * 384 + jB];
        r2 = *(const float4*)&xp[((size_t)(b * L + tC)) * 384 + jC];
    }
    __syncthreads();

    const int bbase = (mrow & 1) * 128 + quad * 8;  // A-frag index: row0=hi, row1=lo
    int par = 0;

    for (int c = 0; c < nch; c++) {
        const int cnt = min(16, len - c * 16);
        // commit staged regs (vmcnt wait lands here, hidden by a full chunk)
        if (sA < cnt) *(float4*)&xbuf[sA * 384 + jA] = r0;
        if (sB < cnt) *(float4*)&xbuf[sB * 384 + jB] = r1;
        if (sC < cnt) *(float4*)&xbuf[sC * 384 + jC] = r2;
        // flush previous chunk's outputs (always a full 16 rows)
        if (c > 0) {
            int p0 = (c - 1) * 16;
            for (int i = tid; i < 16 * 128; i += 512) {
                int ss = i >> 7, kk = i & 127;
                int tt = dir ? (len - 1 - (p0 + ss)) : (p0 + ss);
                out[((size_t)(b * L + tt)) * 256 + dir * 128 + kk] = obuf[i];
            }
        }
        // prefetch chunk c+1 into registers
        if (c + 1 < nch) {
            int ncnt = min(16, len - (c + 1) * 16);
            int base = (c + 1) * 16;
            if (sA < ncnt) {
                int tt = dir ? (len - 1 - (base + sA)) : (base + sA);
                r0 = *(const float4*)&xp[((size_t)(b * L + tt)) * 384 + jA];
            }
            if (sB < ncnt) {
                int tt = dir ? (len - 1 - (base + sB)) : (base + sB);
                r1 = *(const float4*)&xp[((size_t)(b * L + tt)) * 384 + jB];
            }
            if (sC < ncnt) {
                int tt = dir ? (len - 1 - (base + sC)) : (base + sC);
                r2 = *(const float4*)&xp[((size_t)(b * L + tt)) * 384 + jC];
            }
        }
        bar_lds();  // xbuf visible; prev obuf reads complete
        for (int s = 0; s < cnt; s++) {
            // gate-input LDS reads issued early (latency hidden under MFMA)
            float xr, xz, xn;
            if (lane < 16) {
                xr = xbuf[s * 384 + jj];
                xz = xbuf[s * 384 + 128 + jj];
                xn = xbuf[s * 384 + 256 + jj];
            }
            // A-fragments: rows 0/1 = h_hi/h_lo (rows 2-15 duplicates, ignored in C)
            short8 af[4];
#pragma unroll
            for (int kt = 0; kt < 4; kt++) af[kt] = *(const short8*)&hbuf[par][bbase + kt * 32];
            f32x4 acc[3];
#pragma unroll
            for (int g = 0; g < 3; g++) acc[g] = (f32x4){0.f, 0.f, 0.f, 0.f};
#pragma unroll
            for (int kt = 0; kt < 4; kt++)
#pragma unroll
                for (int g = 0; g < 3; g++)
                    acc[g] = __builtin_amdgcn_mfma_f32_16x16x32_bf16(af[kt], wb[g][kt], acc[g], 0, 0, 0);
            // C col = lane (lanes 0-15 = this wave's gate dims); regs 0/1 = W.h_hi/W.h_lo
            if (lane < 16) {
                float hr = acc[0][0] + acc[0][1] + br;
                float hz = acc[1][0] + acc[1][1] + bz;
                float hh = acc[2][0] + acc[2][1] + bn;
                float r = fast_sigmoid(xr + hr);
                float z = fast_sigmoid(xz + hz);
                float n = fast_tanh(xn + r * hh);
                float hn = (1.f - z) * n + z * hcur;
                hcur = hn;
                short hb = f2bf(hn);
                hbuf[par ^ 1][jj] = hb;
                hbuf[par ^ 1][128 + jj] = f2bf(hn - bf2f(hb));
                obuf[s * 128 + jj] = hn;
            }
            par ^= 1;
            bar_lds();  // hbuf[par] ready for all waves; single barrier per step
        }
    }
    // final flush (last chunk, possibly partial)
    {
        int p0 = (nch - 1) * 16;
        int pcnt = len - p0;
        for (int i = tid; i < pcnt * 128; i += 512) {
            int ss = i >> 7, kk = i & 127;
            int tt = dir ? (len - 1 - (p0 + ss)) : (p0 + ss);
            out[((size_t)(b * L + tt)) * 256 + dir * 128 + kk] = obuf[i];
        }
    }
}

extern "C" void kernel_launch(void* const* d_in, const int* in_sizes, int n_in,
                              void* d_out, int out_size, void* d_ws, size_t ws_size,
                              hipStream_t stream) {
    const int B = 4, L = 512, D = 256, H = 128;
    const int M = B * L;  // 2048

    const float* v      = (const float*)d_in[0];
    const int* lengths  = (const int*)d_in[1];
    // d_in[2] = p_mask (bool) — unused, lengths is equivalent
    const float* own_W  = (const float*)d_in[3];
    const float* own_b  = (const float*)d_in[4];
    const float* comp_W = (const float*)d_in[5];
    const float* comp_b = (const float*)d_in[6];
    const float* v_attn = (const float*)d_in[7];
    const float* gate_W = (const float*)d_in[8];
    const float* gate_b = (const float*)d_in[9];
    const float* w_ih_f = (const float*)d_in[10];
    const float* w_hh_f = (const float*)d_in[11];
    const float* b_ih_f = (const float*)d_in[12];
    const float* b_hh_f = (const float*)d_in[13];
    const float* w_ih_b = (const float*)d_in[14];
    const float* w_hh_b = (const float*)d_in[15];
    const float* b_ih_b = (const float*)d_in[16];
    const float* b_hh_b = (const float*)d_in[17];

    float* ws   = (float*)d_ws;
    float* own  = ws;                       // [2048,128]
    float* comp = own + (size_t)M * H;      // [2048,128]
    float* inp  = comp + (size_t)M * H;     // [2048,512]
    float* gated = inp + (size_t)M * 512;   // [2048,512]
    float* xp_f = gated + (size_t)M * 512;  // [2048,384]
    float* xp_b = xp_f + (size_t)M * 384;   // [2048,384]
    float* out  = (float*)d_out;            // [2048,256]

    // 1: own & comp projections in one launch (tiles 0..1 -> own, 2..3 -> comp)
    gemm_bias<<<dim3(4, M / 64), 256, 0, stream>>>(
        v, own_W, own_b, own, comp_W, comp_b, comp, lengths, M, H, D, 2, 0);
    // 2: attention (8 q per block) -> inp = [v, C]
    attn_kernel<<<dim3(B * 64), 512, 0, stream>>>(v, lengths, own, comp, v_attn, inp);
    // 3: gate
    gemm_bias<<<dim3(8, M / 64), 256, 0, stream>>>(
        inp, gate_W, gate_b, gated, gate_W, gate_b, gated, lengths, M, 512, 512, 8, 1);
    // 4: input projections for both GRU directions in one launch
    gemm_bias<<<dim3(12, M / 64), 256, 0, stream>>>(
        gated, w_ih_f, b_ih_f, xp_f, w_ih_b, b_ih_b, xp_b, lengths, M, 384, 512, 6, 0);
    // 5: sequential GRU, one block per (dir, batch)
    gru_kernel<<<dim3(8), 512, 0, stream>>>(xp_f, xp_b, w_hh_f, w_hh_b, b_hh_f, b_hh_b, lengths, out);
}

// Round 12
// 399.560 us; speedup vs baseline: 35.6902x; 1.0878x over previous
//
#include <hip/hip_runtime.h>
#include <hip/hip_bf16.h>

#define NEGINF -1e30f

typedef __attribute__((ext_vector_type(8))) short short8;
typedef __attribute__((ext_vector_type(4))) float f32x4;

// Clamp-free: IEEE inf semantics give exact limits (exp->inf => rcp->0), NaN-free.
__device__ __forceinline__ float fast_sigmoid(float x) {
    return __builtin_amdgcn_rcpf(1.f + __expf(-x));
}
__device__ __forceinline__ float fast_tanh(float x) {
    return 1.f - 2.f * __builtin_amdgcn_rcpf(1.f + __expf(2.f * x));
}
// round-to-nearest-even f32 -> bf16 bits
__device__ __forceinline__ short f2bf(float f) {
    unsigned u = __float_as_uint(f);
    return (short)((u + 0x7fff + ((u >> 16) & 1)) >> 16);
}
__device__ __forceinline__ float bf2f(short b) {
    return __uint_as_float(((unsigned)(unsigned short)b) << 16);
}

// LDS-only workgroup barrier (proven R3-R11): waits lgkmcnt only; in-flight global
// loads/stores are NOT drained. Safe when all cross-thread traffic goes through LDS.
__device__ __forceinline__ void bar_lds() {
    asm volatile("s_waitcnt lgkmcnt(0)\n\ts_barrier" ::: "memory");
}

// ---------------- MFMA GEMM: out[M,N] = A[M,K] @ W[N,K]^T + bias ---------------------
// 64x64 tile, 256 threads = 4 waves (wave = one 32x32 quadrant = 2x2 MFMA tiles).
// A,W staged per k32 into LDS as bf16 hi/lo (parity double-buffer, register prefetch,
// single bar_lds per iter — R8 pipeline). 3-combo MFMA (AhiBhi + AloBhi + AhiBlo)
// keeps ~2^-16 precision (absmax-neutral vs f32). A-frag layout = R10 gbf pattern,
// B-frag = gru wb pattern, C mapping col=lane&15 (n), row=quad*4+reg (m) — all
// HW-proven. Row-tiles past lengths[batch] skipped. mode 1: out = sigmoid(.)*A.
__global__ __launch_bounds__(256) void gemm_bias(
    const float* __restrict__ A,
    const float* __restrict__ W1, const float* __restrict__ b1, float* __restrict__ out1,
    const float* __restrict__ W2, const float* __restrict__ b2, float* __restrict__ out2,
    const int* __restrict__ lengths,
    int M, int N, int K, int nsplit, int mode) {
    const int m0 = blockIdx.y * 64;
    if ((m0 & 511) >= lengths[m0 >> 9]) return;  // uniform per block; rows unread
    __shared__ __align__(16) short Abh[2][2048];  // [parity][64m x 32k] hi
    __shared__ __align__(16) short Abl[2][2048];  // lo
    __shared__ __align__(16) short Bbh[2][2048];  // [parity][64n x 32k] hi
    __shared__ __align__(16) short Bbl[2][2048];  // lo
    const int tid = threadIdx.x;
    int bx = blockIdx.x;
    const float* W = W1; const float* bias = b1; float* out = out1;
    int n0;
    if (bx < nsplit) {
        n0 = bx * 64;
    } else {
        W = W2; bias = b2; out = out2;
        n0 = (bx - nsplit) * 64;
    }
    const int wave = tid >> 6;
    const int lane = tid & 63;
    const int mrow = lane & 15;       // A-frag m index / B-frag n index / C col
    const int quad = lane >> 4;       // k-quad; C rows = quad*4+reg
    const int wm = (wave >> 1) * 32;  // wave quadrant
    const int wn = (wave & 1) * 32;

    // staging: thread covers 8 contiguous k of one row (4 threads/row)
    const int r_ = tid >> 2;          // 0..63
    const int sg = (tid & 3) * 8;     // 0,8,16,24

    f32x4 acc[2][2];
#pragma unroll
    for (int mt = 0; mt < 2; mt++)
#pragma unroll
        for (int nt = 0; nt < 2; nt++) acc[mt][nt] = (f32x4){0.f, 0.f, 0.f, 0.f};

    // preload k-chunk 0
    float4 a0 = *(const float4*)(A + (size_t)(m0 + r_) * K + sg);
    float4 a1 = *(const float4*)(A + (size_t)(m0 + r_) * K + sg + 4);
    float4 w0 = *(const float4*)(W + (size_t)(n0 + r_) * K + sg);
    float4 w1 = *(const float4*)(W + (size_t)(n0 + r_) * K + sg + 4);

    for (int k0 = 0; k0 < K; k0 += 32) {
        const int cur = (k0 >> 5) & 1;
        // convert + commit staged regs (vmcnt wait lands here; full iter in flight)
        {
            float av[8] = {a0.x, a0.y, a0.z, a0.w, a1.x, a1.y, a1.z, a1.w};
            float wv[8] = {w0.x, w0.y, w0.z, w0.w, w1.x, w1.y, w1.z, w1.w};
            short8 ah, al, bh, bl;
#pragma unroll
            for (int j = 0; j < 8; j++) {
                short h = f2bf(av[j]); ah[j] = h; al[j] = f2bf(av[j] - bf2f(h));
                short g = f2bf(wv[j]); bh[j] = g; bl[j] = f2bf(wv[j] - bf2f(g));
            }
            *(short8*)&Abh[cur][r_ * 32 + sg] = ah;
            *(short8*)&Abl[cur][r_ * 32 + sg] = al;
            *(short8*)&Bbh[cur][r_ * 32 + sg] = bh;
            *(short8*)&Bbl[cur][r_ * 32 + sg] = bl;
        }
        // prefetch next k-chunk (stays in flight across bar_lds)
        if (k0 + 32 < K) {
            a0 = *(const float4*)(A + (size_t)(m0 + r_) * K + k0 + 32 + sg);
            a1 = *(const float4*)(A + (size_t)(m0 + r_) * K + k0 + 32 + sg + 4);
            w0 = *(const float4*)(W + (size_t)(n0 + r_) * K + k0 + 32 + sg);
            w1 = *(const float4*)(W + (size_t)(n0 + r_) * K + k0 + 32 + sg + 4);
        }
        bar_lds();  // staged bf16 visible; parity prevents WAR
        short8 Ah[2], Al[2], Bh[2], Bl[2];
#pragma unroll
        for (int t = 0; t < 2; t++) {
            int ar = (wm + t * 16 + mrow) * 32 + quad * 8;
            int br = (wn + t * 16 + mrow) * 32 + quad * 8;
            Ah[t] = *(const short8*)&Abh[cur][ar];
            Al[t] = *(const short8*)&Abl[cur][ar];
            Bh[t] = *(const short8*)&Bbh[cur][br];
            Bl[t] = *(const short8*)&Bbl[cur][br];
        }
#pragma unroll
        for (int mt = 0; mt < 2; mt++)
#pragma unroll
            for (int nt = 0; nt < 2; nt++) {
                acc[mt][nt] = __builtin_amdgcn_mfma_f32_16x16x32_bf16(Ah[mt], Bh[nt], acc[mt][nt], 0, 0, 0);
                acc[mt][nt] = __builtin_amdgcn_mfma_f32_16x16x32_bf16(Al[mt], Bh[nt], acc[mt][nt], 0, 0, 0);
                acc[mt][nt] = __builtin_amdgcn_mfma_f32_16x16x32_bf16(Ah[mt], Bl[nt], acc[mt][nt], 0, 0, 0);
            }
        bar_lds();  // frag reads done before next iter's writes to [cur^1]... (2-bar safety not needed: parity + barrier-per-iter already prevents 2-ahead; this keeps wave skew bounded)
    }
    // epilogue: C[m = quad*4+r][n = mrow] per tile (m89 mapping)
    float bsv[2];
#pragma unroll
    for (int nt = 0; nt < 2; nt++) bsv[nt] = bias[n0 + wn + nt * 16 + mrow];
#pragma unroll
    for (int mt = 0; mt < 2; mt++)
#pragma unroll
        for (int nt = 0; nt < 2; nt++) {
            int n = n0 + wn + nt * 16 + mrow;
#pragma unroll
            for (int r = 0; r < 4; r++) {
                int m = m0 + wm + mt * 16 + quad * 4 + r;
                float val = acc[mt][nt][r] + bsv[nt];
                if (mode == 1) val = fast_sigmoid(val) * A[(size_t)m * K + n];
                out[(size_t)m * N + n] = val;
            }
        }
}

// ---------------- Attention, 8 queries per block (q-tiled, R11) ----------------------
__global__ __launch_bounds__(512) void attn_kernel(
    const float* __restrict__ v, const int* __restrict__ lengths,
    const float* __restrict__ own, const float* __restrict__ comp,
    const float* __restrict__ v_attn, float* __restrict__ inp) {
    const int L = 512, D = 256, H = 128;
    const int b = blockIdx.x >> 6;
    const int q0 = (blockIdx.x & 63) * 8;
    const int len = lengths[b];
    if (q0 >= len) return;  // whole q-tile unread downstream
    const int tid = threadIdx.x;
    const float K2E = 2.8853900817779268f;  // 2*log2(e)
    __shared__ __align__(16) float oKT[128 * 8];   // [h][q] = K2E*own (4 KB)
    __shared__ float va2s[128];                    // -2 * v_attn
    __shared__ __align__(16) float scf[512 * 12];  // [k][q], stride 12 (24 KB)
    __shared__ float inv8[8];

    for (int i = tid; i < 1024; i += 512) {
        int qq = i >> 7, hh = i & 127;
        oKT[hh * 8 + qq] = K2E * own[((size_t)(b * L + q0 + qq)) * H + hh];
    }
    if (tid < 128) va2s[tid] = -2.f * v_attn[tid];
    __syncthreads();

    {
        const int k = tid;
        float acc[8];
#pragma unroll
        for (int q = 0; q < 8; q++) acc[q] = 0.f;
        if (k < len) {
            const float* cp = comp + ((size_t)(b * L + k)) * H;
            for (int h = 0; h < 128; h += 4) {
                float4 c4 = *(const float4*)(cp + h);
                const float* cv = (const float*)&c4;
#pragma unroll
                for (int j = 0; j < 4; j++) {
                    float cK = cv[j] * K2E;
                    float va = va2s[h + j];
                    float4 o0 = *(const float4*)&oKT[(h + j) * 8];      // broadcast
                    float4 o1 = *(const float4*)&oKT[(h + j) * 8 + 4];  // broadcast
                    const float* op0 = (const float*)&o0;
                    const float* op1 = (const float*)&o1;
#pragma unroll
                    for (int q = 0; q < 4; q++) {
                        float r = __builtin_amdgcn_rcpf(1.f + exp2f(cK + op0[q]));
                        acc[q] = fmaf(va, r, acc[q]);
                    }
#pragma unroll
                    for (int q = 0; q < 4; q++) {
                        float r = __builtin_amdgcn_rcpf(1.f + exp2f(cK + op1[q]));
                        acc[4 + q] = fmaf(va, r, acc[4 + q]);
                    }
                }
            }
#pragma unroll
            for (int q = 0; q < 8; q++) acc[q] = __expf(acc[q]);  // bounded, no max pass
        }
        *(float4*)&scf[k * 12] = *(float4*)&acc[0];
        *(float4*)&scf[k * 12 + 4] = *(float4*)&acc[4];
    }
    __syncthreads();

    {
        int w = tid >> 6, l = tid & 63;
        float s = 0.f;
#pragma unroll
        for (int kk = 0; kk < 8; kk++) s += scf[(l + kk * 64) * 12 + w];
#pragma unroll
        for (int off = 1; off < 64; off <<= 1) s += __shfl_xor(s, off);
        if (l == 0) inv8[w] = __builtin_amdgcn_rcpf(s);
    }
    __syncthreads();

    {
        const int d = tid & 255;
        const int qh = tid >> 8;  // 0/1
        float c0 = 0.f, c1 = 0.f, c2 = 0.f, c3 = 0.f;
        const float* vb = v + ((size_t)b * L) * D + d;
        for (int k = 0; k < L; k += 2) {
            float v0 = vb[(size_t)k * D];
            float v1 = vb[(size_t)(k + 1) * D];
            float4 s0 = *(const float4*)&scf[k * 12 + qh * 4];        // broadcast
            float4 s1 = *(const float4*)&scf[(k + 1) * 12 + qh * 4];  // broadcast
            c0 += s0.x * v0 + s1.x * v1;
            c1 += s0.y * v0 + s1.y * v1;
            c2 += s0.z * v0 + s1.z * v1;
            c3 += s0.w * v0 + s1.w * v1;
        }
        float cc[4] = {c0, c1, c2, c3};
#pragma unroll
        for (int j = 0; j < 4; j++) {
            int q = q0 + qh * 4 + j;
            size_t row = ((size_t)(b * L + q)) * 512;
            inp[row + 256 + d] = cc[j] * inv8[qh * 4 + j];
            inp[row + d] = v[((size_t)(b * L + q)) * D + d];
        }
    }
}

// ---------------- Bidirectional GRU recurrence (operand-swapped MFMA, R9) -----------
__global__ __launch_bounds__(512, 2) void gru_kernel(
    const float* __restrict__ xp_f, const float* __restrict__ xp_b,
    const float* __restrict__ w_hh_f, const float* __restrict__ w_hh_b,
    const float* __restrict__ b_hh_f, const float* __restrict__ b_hh_b,
    const int* __restrict__ lengths, float* __restrict__ out) {
    const int L = 512, H = 128;
    const int dir = blockIdx.x >> 2;
    const int b = blockIdx.x & 3;
    const float* xp = dir ? xp_b : xp_f;
    const float* w_hh = dir ? w_hh_b : w_hh_f;
    const float* b_hh = dir ? b_hh_b : b_hh_f;
    const int tid = threadIdx.x;
    const int wave = tid >> 6;
    const int lane = tid & 63;
    const int mrow = lane & 15;
    const int quad = lane >> 4;
    const int jj = 16 * wave + lane;  // gate dim for lanes lane<16

    __shared__ __align__(16) short hbuf[2][256];   // [parity][hi 0..127 | lo 128..255]
    __shared__ __align__(16) float xbuf[16 * 384]; // xp chunk stage (24 KB)
    __shared__ __align__(16) float obuf[16 * 128]; // output stage (8 KB)

    short8 wb[3][4];
#pragma unroll
    for (int g = 0; g < 3; g++) {
        int row = g * 128 + 16 * wave + mrow;
#pragma unroll
        for (int kt = 0; kt < 4; kt++) {
            const float* wp = w_hh + (size_t)row * H + kt * 32 + quad * 8;
            float4 w0 = *(const float4*)(wp);
            float4 w1 = *(const float4*)(wp + 4);
            float wv[8] = {w0.x, w0.y, w0.z, w0.w, w1.x, w1.y, w1.z, w1.w};
            short8 hi8;
#pragma unroll
            for (int k = 0; k < 8; k++) hi8[k] = f2bf(wv[k]);
            wb[g][kt] = hi8;
        }
    }
    float br = 0.f, bz = 0.f, bn = 0.f, hcur = 0.f;
    if (lane < 16) {
        br = b_hh[jj];
        bz = b_hh[128 + jj];
        bn = b_hh[256 + jj];
    }

    const int len = lengths[b];
    for (int idx = tid; idx < (L - len) * 128; idx += 512) {
        int tt = len + (idx >> 7);
        int kk = idx & 127;
        out[((size_t)(b * L + tt)) * 256 + dir * 128 + kk] = 0.f;
    }
    if (tid < 256) hbuf[0][tid] = 0;

    const int f1 = tid + 512, f2 = tid + 1024;
    const int sA = tid / 96, jA = (tid % 96) * 4;
    const int sB = f1 / 96, jB = (f1 % 96) * 4;
    const int sC = f2 / 96, jC = (f2 % 96) * 4;

    const int nch = (len + 15) >> 4;  // len >= 256 so chunk 0 is full
    float4 r0, r1, r2;
    {
        int tA = dir ? (len - 1 - sA) : sA;
        int tB = dir ? (len - 1 - sB) : sB;
        int tC = dir ? (len - 1 - sC) : sC;
        r0 = *(const float4*)&xp[((size_t)(b * L + tA)) * 384 + jA];
        r1 = *(const float4*)&xp[((size_t)(b * L + tB)) * 384 + jB];
        r2 = *(const float4*)&xp[((size_t)(b * L + tC)) * 384 + jC];
    }
    __syncthreads();

    const int bbase = (mrow & 1) * 128 + quad * 8;  // A-frag index: row0=hi, row1=lo
    int par = 0;

    for (int c = 0; c < nch; c++) {
        const int cnt = min(16, len - c * 16);
        if (sA < cnt) *(float4*)&xbuf[sA * 384 + jA] = r0;
        if (sB < cnt) *(float4*)&xbuf[sB * 384 + jB] = r1;
        if (sC < cnt) *(float4*)&xbuf[sC * 384 + jC] = r2;
        if (c > 0) {
            int p0 = (c - 1) * 16;
            for (int i = tid; i < 16 * 128; i += 512) {
                int ss = i >> 7, kk = i & 127;
                int tt = dir ? (len - 1 - (p0 + ss)) : (p0 + ss);
                out[((size_t)(b * L + tt)) * 256 + dir * 128 + kk] = obuf[i];
            }
        }
        if (c + 1 < nch) {
            int ncnt = min(16, len - (c + 1) * 16);
            int base = (c + 1) * 16;
            if (sA < ncnt) {
                int tt = dir ? (len - 1 - (base + sA)) : (base + sA);
                r0 = *(const float4*)&xp[((size_t)(b * L + tt)) * 384 + jA];
            }
            if (sB < ncnt) {
                int tt = dir ? (len - 1 - (base + sB)) : (base + sB);
                r1 = *(const float4*)&xp[((size_t)(b * L + tt)) * 384 + jB];
            }
            if (sC < ncnt) {
                int tt = dir ? (len - 1 - (base + sC)) : (base + sC);
                r2 = *(const float4*)&xp[((size_t)(b * L + tt)) * 384 + jC];
            }
        }
        bar_lds();  // xbuf visible; prev obuf reads complete
        for (int s = 0; s < cnt; s++) {
            float xr, xz, xn;
            if (lane < 16) {
                xr = xbuf[s * 384 + jj];
                xz = xbuf[s * 384 + 128 + jj];
                xn = xbuf[s * 384 + 256 + jj];
            }
            short8 af[4];
#pragma unroll
            for (int kt = 0; kt < 4; kt++) af[kt] = *(const short8*)&hbuf[par][bbase + kt * 32];
            f32x4 acc[3];
#pragma unroll
            for (int g = 0; g < 3; g++) acc[g] = (f32x4){0.f, 0.f, 0.f, 0.f};
#pragma unroll
            for (int kt = 0; kt < 4; kt++)
#pragma unroll
                for (int g = 0; g < 3; g++)
                    acc[g] = __builtin_amdgcn_mfma_f32_16x16x32_bf16(af[kt], wb[g][kt], acc[g], 0, 0, 0);
            if (lane < 16) {
                float hr = acc[0][0] + acc[0][1] + br;
                float hz = acc[1][0] + acc[1][1] + bz;
                float hh = acc[2][0] + acc[2][1] + bn;
                float r = fast_sigmoid(xr + hr);
                float z = fast_sigmoid(xz + hz);
                float n = fast_tanh(xn + r * hh);
                float hn = (1.f - z) * n + z * hcur;
                hcur = hn;
                short hb = f2bf(hn);
                hbuf[par ^ 1][jj] = hb;
                hbuf[par ^ 1][128 + jj] = f2bf(hn - bf2f(hb));
                obuf[s * 128 + jj] = hn;
            }
            par ^= 1;
            bar_lds();  // hbuf[par] ready for all waves; single barrier per step
        }
    }
    {
        int p0 = (nch - 1) * 16;
        int pcnt = len - p0;
        for (int i = tid; i < pcnt * 128; i += 512) {
            int ss = i >> 7, kk = i & 127;
            int tt = dir ? (len - 1 - (p0 + ss)) : (p0 + ss);
            out[((size_t)(b * L + tt)) * 256 + dir * 128 + kk] = obuf[i];
        }
    }
}

extern "C" void kernel_launch(void* const* d_in, const int* in_sizes, int n_in,
                              void* d_out, int out_size, void* d_ws, size_t ws_size,
                              hipStream_t stream) {
    const int B = 4, L = 512, D = 256, H = 128;
    const int M = B * L;  // 2048

    const float* v      = (const float*)d_in[0];
    const int* lengths  = (const int*)d_in[1];
    const float* own_W  = (const float*)d_in[3];
    const float* own_b  = (const float*)d_in[4];
    const float* comp_W = (const float*)d_in[5];
    const float* comp_b = (const float*)d_in[6];
    const float* v_attn = (const float*)d_in[7];
    const float* gate_W = (const float*)d_in[8];
    const float* gate_b = (const float*)d_in[9];
    const float* w_ih_f = (const float*)d_in[10];
    const float* w_hh_f = (const float*)d_in[11];
    const float* b_ih_f = (const float*)d_in[12];
    const float* b_hh_f = (const float*)d_in[13];
    const float* w_ih_b = (const float*)d_in[14];
    const float* w_hh_b = (const float*)d_in[15];
    const float* b_ih_b = (const float*)d_in[16];
    const float* b_hh_b = (const float*)d_in[17];

    float* ws   = (float*)d_ws;
    float* own  = ws;                       // [2048,128]
    float* comp = own + (size_t)M * H;      // [2048,128]
    float* inp  = comp + (size_t)M * H;     // [2048,512]
    float* gated = inp + (size_t)M * 512;   // [2048,512]
    float* xp_f = gated + (size_t)M * 512;  // [2048,384]
    float* xp_b = xp_f + (size_t)M * 384;   // [2048,384]
    float* out  = (float*)d_out;            // [2048,256]

    // 1: own & comp projections in one launch (tiles 0..1 -> own, 2..3 -> comp)
    gemm_bias<<<dim3(4, M / 64), 256, 0, stream>>>(
        v, own_W, own_b, own, comp_W, comp_b, comp, lengths, M, H, D, 2, 0);
    // 2: attention (8 q per block) -> inp = [v, C]
    attn_kernel<<<dim3(B * 64), 512, 0, stream>>>(v, lengths, own, comp, v_attn, inp);
    // 3: gate
    gemm_bias<<<dim3(8, M / 64), 256, 0, stream>>>(
        inp, gate_W, gate_b, gated, gate_W, gate_b, gated, lengths, M, 512, 512, 8, 1);
    // 4: input projections for both GRU directions in one launch
    gemm_bias<<<dim3(12, M / 64), 256, 0, stream>>>(
        gated, w_ih_f, b_ih_f, xp_f, w_ih_b, b_ih_b, xp_b, lengths, M, 384, 512, 6, 0);
    // 5: sequential GRU, one block per (dir, batch)
    gru_kernel<<<dim3(8), 512, 0, stream>>>(xp_f, xp_b, w_hh_f, w_hh_b, b_hh_f, b_hh_b, lengths, out);
}